// Round 1
// baseline (580.546 us; speedup 1.0000x reference)
//
#include <hip/hip_runtime.h>

// Problem constants (from reference): B=64, C=2048, H=W=24 -> HW=576, 16 classes.
constexpr int B  = 64;
constexpr int C  = 2048;
constexpr int HW = 576;
constexpr int PQ = HW / 4;      // 144 float4 "p-quads" per image row
constexpr int SPLIT  = 16;      // C-dimension split for parallelism
constexpr int CCHUNK = C / SPLIT; // 128 channels per thread

// ---------------------------------------------------------------------------
// Kernel 1: lum[t][b][p] = sum_c feat[t][b][c][p]^2    (t=0: feat_v, t=1: feat_i)
// Memory-bound streaming pass over 604 MB. Thread handles one (b, p-quad,
// c-chunk); consecutive threads have consecutive p-quads -> each wave issues
// 64 x 16B = 1 KiB contiguous loads per c-iteration. Partial sums combined
// via float atomics (16 writers/address, lum buffer is L2-resident).
// ---------------------------------------------------------------------------
__global__ __launch_bounds__(256) void lum_kernel(const float* __restrict__ fv,
                                                  const float* __restrict__ fi,
                                                  float* __restrict__ lum) {
    const float* src = blockIdx.y ? fi : fv;
    float* dst = lum + (size_t)blockIdx.y * B * HW;

    int tid  = blockIdx.x * 256 + threadIdx.x;
    int pq   = tid % PQ;
    int rest = tid / PQ;
    int b    = rest % B;
    int s    = rest / B;                 // c-chunk index, 0..SPLIT-1

    const float4* base = (const float4*)(src + (size_t)b * C * HW) + pq;
    float4 acc = make_float4(0.f, 0.f, 0.f, 0.f);
    int c0 = s * CCHUNK;
#pragma unroll 8
    for (int c = c0; c < c0 + CCHUNK; ++c) {
        float4 x = base[(size_t)c * PQ];
        acc.x = fmaf(x.x, x.x, acc.x);
        acc.y = fmaf(x.y, x.y, acc.y);
        acc.z = fmaf(x.z, x.z, acc.z);
        acc.w = fmaf(x.w, x.w, acc.w);
    }
    float* d = dst + b * HW + pq * 4;
    atomicAdd(d + 0, acc.x);
    atomicAdd(d + 1, acc.y);
    atomicAdd(d + 2, acc.z);
    atomicAdd(d + 3, acc.w);
}

// ---------------------------------------------------------------------------
// Kernel 2: one block per row i. Computes, for all j:
//   cross[i,j] = dot(lum_v[i], lum_i[j]) ; ii[j] = dot(lum_i[j], lum_i[j])
//   mse[i,j]   = mean_v2[i] + ii[j]/HW - 2*cross[i,j]/HW
// then masked (same label, i!=j) sum + count -> global double accumulators.
// Double accumulation: mse is a ~300:1 cancellation of ~2.4e9-magnitude sums;
// fp32 would risk the absmax threshold.
// ---------------------------------------------------------------------------
__global__ __launch_bounds__(256) void pair_kernel(const float* __restrict__ lum,
                                                   const int* __restrict__ labels,
                                                   double* __restrict__ acc) {
    const float* lum_v = lum;
    const float* lum_i = lum + B * HW;
    const int i = blockIdx.x;
    const int t = threadIdx.x;

    __shared__ float  lv[HW];
    __shared__ double red[256];
    __shared__ double sc[4][64];
    __shared__ double si[4][64];

    for (int p = t; p < HW; p += 256) lv[p] = lum_v[i * HW + p];
    __syncthreads();

    // mean_v2[i] = sum_p lv[p]^2 / HW  (block reduction)
    double mv = 0.0;
    for (int p = t; p < HW; p += 256) { double x = (double)lv[p]; mv += x * x; }
    red[t] = mv;
    __syncthreads();
    for (int off = 128; off > 0; off >>= 1) {
        if (t < off) red[t] += red[t + off];
        __syncthreads();
    }
    const double mean_v2 = red[0] / (double)HW;

    // 4 threads per j: quarter-range partial dots
    const int j = t & 63;
    const int q = t >> 6;
    const float* li = lum_i + j * HW;
    double cpart = 0.0, spart = 0.0;
    for (int p = q * (HW / 4); p < (q + 1) * (HW / 4); ++p) {
        double x = (double)li[p];
        cpart += (double)lv[p] * x;
        spart += x * x;
    }
    sc[q][j] = cpart;
    si[q][j] = spart;
    __syncthreads();

    if (t < 64) {  // exactly one wave
        double cross = sc[0][t] + sc[1][t] + sc[2][t] + sc[3][t];
        double ii    = si[0][t] + si[1][t] + si[2][t] + si[3][t];
        double mse   = mean_v2 + ii / (double)HW - 2.0 * cross / (double)HW;
        bool m = (labels[i] == labels[t]) && (t != i);
        double val = m ? mse : 0.0;
        double cnt = m ? 1.0 : 0.0;
        for (int off = 32; off > 0; off >>= 1) {
            val += __shfl_down(val, off);
            cnt += __shfl_down(cnt, off);
        }
        if (t == 0) {
            atomicAdd(&acc[0], val);
            atomicAdd(&acc[1], cnt);
        }
    }
}

__global__ void final_kernel(const double* __restrict__ acc, float* __restrict__ out) {
    double cnt = acc[1];
    out[0] = (cnt > 0.0) ? (float)(acc[0] / cnt) : 0.0f;
}

extern "C" void kernel_launch(void* const* d_in, const int* in_sizes, int n_in,
                              void* d_out, int out_size, void* d_ws, size_t ws_size,
                              hipStream_t stream) {
    const float* fv     = (const float*)d_in[0];
    const float* fi     = (const float*)d_in[1];
    const int*   labels = (const int*)d_in[2];
    float*       out    = (float*)d_out;

    // Workspace layout: lum[2][B][HW] fp32, then double acc[2] = {total, count}
    float*  lum = (float*)d_ws;
    size_t  lum_bytes = (size_t)2 * B * HW * sizeof(float);   // 294912, 8B-aligned
    double* acc = (double*)((char*)d_ws + lum_bytes);

    hipMemsetAsync(d_ws, 0, lum_bytes + 2 * sizeof(double), stream);

    dim3 grid1(PQ * B * SPLIT / 256, 2);  // (576, 2)
    lum_kernel<<<grid1, 256, 0, stream>>>(fv, fi, lum);
    pair_kernel<<<B, 256, 0, stream>>>(lum, labels, acc);
    final_kernel<<<1, 1, 0, stream>>>(acc, out);
}

// Round 2
// 580.083 us; speedup vs baseline: 1.0008x; 1.0008x over previous
//
#include <hip/hip_runtime.h>

// Problem constants (from reference): B=64, C=2048, H=W=24 -> HW=576, 16 classes.
constexpr int B  = 64;
constexpr int C  = 2048;
constexpr int HW = 576;
constexpr int PQ = HW / 4;        // 144 float4 "p-quads" per image row
constexpr int SPLIT  = 32;        // C-dimension split: 2304 blocks = 9/CU (was 4.5/CU)
constexpr int CCHUNK = C / SPLIT; // 64 channels per thread

// ---------------------------------------------------------------------------
// Kernel 1: lum[t][b][p] = sum_c feat[t][b][c][p]^2    (t=0: feat_v, t=1: feat_i)
// Memory-bound streaming pass over 604 MB (roofline ~96 us @ 6.3 TB/s).
// Thread handles one (b, p-quad, c-chunk); consecutive lanes have consecutive
// p-quads -> 1 KiB contiguous per wave per c-iteration. SPLIT=32 gives
// 9 blocks/CU for a smooth tail (4.5/CU cost ~50 us of imbalance in R1).
// Partials combined via float atomics into the L2-resident 295 KB lum buffer.
// ---------------------------------------------------------------------------
__global__ __launch_bounds__(256) void lum_kernel(const float* __restrict__ fv,
                                                  const float* __restrict__ fi,
                                                  float* __restrict__ lum) {
    const float* src = blockIdx.y ? fi : fv;
    float* dst = lum + (size_t)blockIdx.y * B * HW;

    int tid  = blockIdx.x * 256 + threadIdx.x;
    int pq   = tid % PQ;
    int rest = tid / PQ;
    int b    = rest % B;
    int s    = rest / B;                 // c-chunk index, 0..SPLIT-1

    const float4* base = (const float4*)(src + (size_t)b * C * HW) + pq;
    float4 acc = make_float4(0.f, 0.f, 0.f, 0.f);
    int c0 = s * CCHUNK;
#pragma unroll 16
    for (int c = c0; c < c0 + CCHUNK; ++c) {
        float4 x = base[(size_t)c * PQ];
        acc.x = fmaf(x.x, x.x, acc.x);
        acc.y = fmaf(x.y, x.y, acc.y);
        acc.z = fmaf(x.z, x.z, acc.z);
        acc.w = fmaf(x.w, x.w, acc.w);
    }
    float* d = dst + b * HW + pq * 4;
    atomicAdd(d + 0, acc.x);
    atomicAdd(d + 1, acc.y);
    atomicAdd(d + 2, acc.z);
    atomicAdd(d + 3, acc.w);
}

// ---------------------------------------------------------------------------
// Kernel 2: one block per row i. Computes, for all j:
//   cross[i,j] = dot(lum_v[i], lum_i[j]) ; ii[j] = dot(lum_i[j], lum_i[j])
//   mse[i,j]   = mean_v2[i] + ii[j]/HW - 2*cross[i,j]/HW
// then masked (same label, i!=j) sum + count -> global double accumulators.
// Double accumulation: mse is a large cancellation of ~2.4e9-magnitude sums;
// fp32 would risk the absmax threshold. (absmax was 0.0 in R1.)
// ---------------------------------------------------------------------------
__global__ __launch_bounds__(256) void pair_kernel(const float* __restrict__ lum,
                                                   const int* __restrict__ labels,
                                                   double* __restrict__ acc) {
    const float* lum_v = lum;
    const float* lum_i = lum + B * HW;
    const int i = blockIdx.x;
    const int t = threadIdx.x;

    __shared__ float  lv[HW];
    __shared__ double red[256];
    __shared__ double sc[4][64];
    __shared__ double si[4][64];

    for (int p = t; p < HW; p += 256) lv[p] = lum_v[i * HW + p];
    __syncthreads();

    // mean_v2[i] = sum_p lv[p]^2 / HW  (block reduction)
    double mv = 0.0;
    for (int p = t; p < HW; p += 256) { double x = (double)lv[p]; mv += x * x; }
    red[t] = mv;
    __syncthreads();
    for (int off = 128; off > 0; off >>= 1) {
        if (t < off) red[t] += red[t + off];
        __syncthreads();
    }
    const double mean_v2 = red[0] / (double)HW;

    // 4 threads per j: quarter-range partial dots
    const int j = t & 63;
    const int q = t >> 6;
    const float* li = lum_i + j * HW;
    double cpart = 0.0, spart = 0.0;
    for (int p = q * (HW / 4); p < (q + 1) * (HW / 4); ++p) {
        double x = (double)li[p];
        cpart += (double)lv[p] * x;
        spart += x * x;
    }
    sc[q][j] = cpart;
    si[q][j] = spart;
    __syncthreads();

    if (t < 64) {  // exactly one wave
        double cross = sc[0][t] + sc[1][t] + sc[2][t] + sc[3][t];
        double ii    = si[0][t] + si[1][t] + si[2][t] + si[3][t];
        double mse   = mean_v2 + ii / (double)HW - 2.0 * cross / (double)HW;
        bool m = (labels[i] == labels[t]) && (t != i);
        double val = m ? mse : 0.0;
        double cnt = m ? 1.0 : 0.0;
        for (int off = 32; off > 0; off >>= 1) {
            val += __shfl_down(val, off);
            cnt += __shfl_down(cnt, off);
        }
        if (t == 0) {
            atomicAdd(&acc[0], val);
            atomicAdd(&acc[1], cnt);
        }
    }
}

__global__ void final_kernel(const double* __restrict__ acc, float* __restrict__ out) {
    double cnt = acc[1];
    out[0] = (cnt > 0.0) ? (float)(acc[0] / cnt) : 0.0f;
}

extern "C" void kernel_launch(void* const* d_in, const int* in_sizes, int n_in,
                              void* d_out, int out_size, void* d_ws, size_t ws_size,
                              hipStream_t stream) {
    const float* fv     = (const float*)d_in[0];
    const float* fi     = (const float*)d_in[1];
    const int*   labels = (const int*)d_in[2];
    float*       out    = (float*)d_out;

    // Workspace layout: lum[2][B][HW] fp32, then double acc[2] = {total, count}
    float*  lum = (float*)d_ws;
    size_t  lum_bytes = (size_t)2 * B * HW * sizeof(float);   // 294912, 8B-aligned
    double* acc = (double*)((char*)d_ws + lum_bytes);

    hipMemsetAsync(d_ws, 0, lum_bytes + 2 * sizeof(double), stream);

    dim3 grid1(PQ * B * SPLIT / 256, 2);  // (1152, 2) = 2304 blocks, 9/CU
    lum_kernel<<<grid1, 256, 0, stream>>>(fv, fi, lum);
    pair_kernel<<<B, 256, 0, stream>>>(lum, labels, acc);
    final_kernel<<<1, 1, 0, stream>>>(acc, out);
}

// Round 3
// 574.570 us; speedup vs baseline: 1.0104x; 1.0096x over previous
//
#include <hip/hip_runtime.h>

// Problem constants (from reference): B=64, C=2048, H=W=24 -> HW=576, 16 classes.
constexpr int B  = 64;
constexpr int C  = 2048;
constexpr int HW = 576;
constexpr int PQ = HW / 4;   // 144 float4 "p-quads" per image row

// ---------------------------------------------------------------------------
// Kernel 1: lum[t][b][p] = sum_c feat[t][b][c][p]^2   (t=0: feat_v, 1: feat_i)
// 604 MB single-pass stream, roofline ~96 us @ 6.3 TB/s.
//
// PERFECT BALANCE: 2048 blocks (exactly 8/CU -> one fully-resident cohort,
// no second round) x 256 threads; 37,748,736 float4 loads / 524,288 threads
// = exactly 72 per thread. 16 blocks per (t,b) slab, 9 units per block,
// 8 c's per thread per unit. R1/R2 had ~80 us work quanta of cohort
// imbalance (4.5/CU and 9-vs-8/CU) which this eliminates.
//
// Accumulation: per-WAVE LDS float4[144] (at every step the 64 lanes hit 64
// distinct pq's since 144>64, and a wave's DS ops execute in order -> no
// races, no LDS atomics), then 4 global float atomics per p per block
// (1.18M total, 16 writers/address, L2-resident target).
// ---------------------------------------------------------------------------
__global__ __launch_bounds__(256) void lum_kernel(const float* __restrict__ fv,
                                                  const float* __restrict__ fi,
                                                  float* __restrict__ lum) {
    __shared__ float4 wbuf[4][PQ];

    const int tid  = threadIdx.x;
    const int wave = tid >> 6;
    const int lane = tid & 63;
    float4* my = wbuf[wave];

    // Zero this wave's buffer (same-wave DS in-order => visible to unit loop)
    for (int p = lane; p < PQ; p += 64) my[p] = make_float4(0.f, 0.f, 0.f, 0.f);

    const int slab = blockIdx.x >> 4;          // 0..127 = t*64 + b
    const int t    = slab >> 6;
    const int bb   = slab & 63;
    const float4* base = (const float4*)((t ? fi : fv) + (size_t)bb * C * HW);

    // within-slab thread-unit id; h in [0, 36864): pq = h%144, s = h/144
    const int h0 = ((blockIdx.x & 15) * 9) * 256 + tid;

    for (int k = 0; k < 9; ++k) {
        int h  = h0 + k * 256;
        int s  = h / PQ;                // c-chunk 0..255 (magic-mul)
        int pq = h - s * PQ;
        const float4* p0 = base + (size_t)(s * 8) * PQ + pq;
        float4 a = make_float4(0.f, 0.f, 0.f, 0.f);
#pragma unroll
        for (int j = 0; j < 8; ++j) {
            float4 x = p0[(size_t)j * PQ];
            a.x = fmaf(x.x, x.x, a.x);
            a.y = fmaf(x.y, x.y, a.y);
            a.z = fmaf(x.z, x.z, a.z);
            a.w = fmaf(x.w, x.w, a.w);
        }
        float4 cur = my[pq];
        cur.x += a.x; cur.y += a.y; cur.z += a.z; cur.w += a.w;
        my[pq] = cur;
    }
    __syncthreads();

    if (tid < PQ) {
        float4 s0 = wbuf[0][tid], s1 = wbuf[1][tid], s2 = wbuf[2][tid], s3 = wbuf[3][tid];
        float4 r;
        r.x = (s0.x + s1.x) + (s2.x + s3.x);
        r.y = (s0.y + s1.y) + (s2.y + s3.y);
        r.z = (s0.z + s1.z) + (s2.z + s3.z);
        r.w = (s0.w + s1.w) + (s2.w + s3.w);
        float* d = lum + (size_t)slab * HW + tid * 4;
        atomicAdd(d + 0, r.x);
        atomicAdd(d + 1, r.y);
        atomicAdd(d + 2, r.z);
        atomicAdd(d + 3, r.w);
    }
}

// ---------------------------------------------------------------------------
// Kernel 2: one block per row i. Computes, for all j:
//   cross[i,j] = dot(lum_v[i], lum_i[j]) ; ii[j] = dot(lum_i[j], lum_i[j])
//   mse[i,j]   = mean_v2[i] + ii[j]/HW - 2*cross[i,j]/HW
// then masked (same label, i!=j) sum + count -> global double accumulators.
// Double accumulation: mse is a large cancellation of ~2.4e9-magnitude sums;
// fp32 would risk the absmax threshold. (absmax was 0.0 in R1/R2.)
// ---------------------------------------------------------------------------
__global__ __launch_bounds__(256) void pair_kernel(const float* __restrict__ lum,
                                                   const int* __restrict__ labels,
                                                   double* __restrict__ acc) {
    const float* lum_v = lum;
    const float* lum_i = lum + B * HW;
    const int i = blockIdx.x;
    const int t = threadIdx.x;

    __shared__ float  lv[HW];
    __shared__ double red[256];
    __shared__ double sc[4][64];
    __shared__ double si[4][64];

    for (int p = t; p < HW; p += 256) lv[p] = lum_v[i * HW + p];
    __syncthreads();

    // mean_v2[i] = sum_p lv[p]^2 / HW  (block reduction)
    double mv = 0.0;
    for (int p = t; p < HW; p += 256) { double x = (double)lv[p]; mv += x * x; }
    red[t] = mv;
    __syncthreads();
    for (int off = 128; off > 0; off >>= 1) {
        if (t < off) red[t] += red[t + off];
        __syncthreads();
    }
    const double mean_v2 = red[0] / (double)HW;

    // 4 threads per j: quarter-range partial dots
    const int j = t & 63;
    const int q = t >> 6;
    const float* li = lum_i + j * HW;
    double cpart = 0.0, spart = 0.0;
    for (int p = q * (HW / 4); p < (q + 1) * (HW / 4); ++p) {
        double x = (double)li[p];
        cpart += (double)lv[p] * x;
        spart += x * x;
    }
    sc[q][j] = cpart;
    si[q][j] = spart;
    __syncthreads();

    if (t < 64) {  // exactly one wave
        double cross = sc[0][t] + sc[1][t] + sc[2][t] + sc[3][t];
        double ii    = si[0][t] + si[1][t] + si[2][t] + si[3][t];
        double mse   = mean_v2 + ii / (double)HW - 2.0 * cross / (double)HW;
        bool m = (labels[i] == labels[t]) && (t != i);
        double val = m ? mse : 0.0;
        double cnt = m ? 1.0 : 0.0;
        for (int off = 32; off > 0; off >>= 1) {
            val += __shfl_down(val, off);
            cnt += __shfl_down(cnt, off);
        }
        if (t == 0) {
            atomicAdd(&acc[0], val);
            atomicAdd(&acc[1], cnt);
        }
    }
}

__global__ void final_kernel(const double* __restrict__ acc, float* __restrict__ out) {
    double cnt = acc[1];
    out[0] = (cnt > 0.0) ? (float)(acc[0] / cnt) : 0.0f;
}

extern "C" void kernel_launch(void* const* d_in, const int* in_sizes, int n_in,
                              void* d_out, int out_size, void* d_ws, size_t ws_size,
                              hipStream_t stream) {
    const float* fv     = (const float*)d_in[0];
    const float* fi     = (const float*)d_in[1];
    const int*   labels = (const int*)d_in[2];
    float*       out    = (float*)d_out;

    // Workspace layout: lum[2][B][HW] fp32, then double acc[2] = {total, count}
    float*  lum = (float*)d_ws;
    size_t  lum_bytes = (size_t)2 * B * HW * sizeof(float);   // 294912, 8B-aligned
    double* acc = (double*)((char*)d_ws + lum_bytes);

    hipMemsetAsync(d_ws, 0, lum_bytes + 2 * sizeof(double), stream);

    lum_kernel<<<2048, 256, 0, stream>>>(fv, fi, lum);   // exactly 8 blocks/CU
    pair_kernel<<<B, 256, 0, stream>>>(lum, labels, acc);
    final_kernel<<<1, 1, 0, stream>>>(acc, out);
}